// Round 14
// baseline (2098.947 us; speedup 1.0000x reference)
//
#include <hip/hip_runtime.h>

#define B_ 128
#define T_ 270
#define XR 4104   // 8 + 64*64
#define H_ 256

typedef __attribute__((ext_vector_type(8))) short short8v;
typedef __attribute__((ext_vector_type(4))) float f32x4;

__device__ inline unsigned short f2bf(float f) {
  unsigned u = __builtin_bit_cast(unsigned, f);
  u += 0x7fffu + ((u >> 16) & 1u);
  return (unsigned short)(u >> 16);
}
__device__ inline float sigm(float x) { return 1.0f / (1.0f + __expf(-x)); }
__device__ inline float tanh_f(float x) {
  float t = __expf(-2.0f * fabsf(x));
  float r = (1.0f - t) / (1.0f + t);
  return copysignf(r, x);
}
__device__ inline short8v pack8(const float* p) {
  float4 a = *(const float4*)p, b = *(const float4*)(p + 4);
  short8v v;
  v[0] = (short)f2bf(a.x); v[1] = (short)f2bf(a.y);
  v[2] = (short)f2bf(a.z); v[3] = (short)f2bf(a.w);
  v[4] = (short)f2bf(b.x); v[5] = (short)f2bf(b.y);
  v[6] = (short)f2bf(b.z); v[7] = (short)f2bf(b.w);
  return v;
}
__device__ inline short8v pinned(short8v v) {       // arch-VGPR pin
  union { short8v s; float f[4]; } u;
  u.s = v;
  asm volatile("" : "+v"(u.f[0]), "+v"(u.f[1]), "+v"(u.f[2]), "+v"(u.f[3]));
  return u.s;
}
__device__ inline short8v pinned_a(short8v v) {     // AGPR pin
  union { short8v s; float f[4]; } u;
  u.s = v;
  asm volatile("" : "+a"(u.f[0]), "+a"(u.f[1]), "+a"(u.f[2]), "+a"(u.f[3]));
  return u.s;
}
#define MFMA(a, b, c) __builtin_amdgcn_mfma_f32_16x16x32_bf16((a), (b), (c), 0, 0, 0)

// ws layout (bytes)
#define FEAT16_B ((size_t)T_ * B_ * 16 * 2)        // 1,105,920
#define SPACK_B  ((size_t)8 * 8 * 9 * 64 * 8 * 2)  //   589,824
#define HB_B     ((size_t)2 * 16 * 16 * 128 * 2)   //   131,072
#define HP_B     ((size_t)2 * 16 * 16 * 4 * 4)     //     8,192
#define FLAGS_B  ((size_t)8 * 16 * 4)              //       512
#define WS_NEED  (FEAT16_B + SPACK_B + HB_B + HP_B + FLAGS_B)

// ---------------------------------------------------------------------------
// Kernel 1: per-(b,t) CNN tower (r8 verbatim); zeroes the 8 block flags.
// ---------------------------------------------------------------------------
__global__ __launch_bounds__(256) void cnn_kernel(
    const float* __restrict__ x,
    const float* __restrict__ c1w_, const float* __restrict__ c1b_,
    const float* __restrict__ c2w_, const float* __restrict__ c2b_,
    const float* __restrict__ fcw, const float* __restrict__ fcb,
    unsigned short* __restrict__ feat16, unsigned* __restrict__ flags)
{
  __shared__ float img[64 * 68];
  __shared__ float p1[2 * 15 * 16];
  __shared__ float p2[36];
  __shared__ float wsm[96];
  const int tid = threadIdx.x;
  const int bt = blockIdx.x;
  const int b = bt & 127, t = bt >> 7;

  if (bt == 0 && tid < 8)
    __hip_atomic_store(flags + tid * 16, 0u, __ATOMIC_RELAXED, __HIP_MEMORY_SCOPE_AGENT);

  const float* src = x + ((long)b * T_ + t) * XR;

  if (tid < 18) wsm[tid] = c1w_[tid];
  else if (tid < 20) wsm[tid] = c1b_[tid - 18];
  else if (tid < 92) wsm[tid] = c2w_[tid - 20];
  else if (tid < 96) wsm[tid] = c2b_[tid - 92];

  {
    const float4* s4 = (const float4*)(src + 8);
#pragma unroll
    for (int i0 = 0; i0 < 4; i0++) {
      int i = tid + i0 * 256;
      float4 v = s4[i];
      int e = i * 4;
      *((float4*)&img[(e >> 6) * 68 + (e & 63)]) = v;
    }
  }
  __syncthreads();

  if (tid < 225) {
    int py = tid / 15, px = tid - (tid / 15) * 15;
    float w0[9], w1[9];
#pragma unroll
    for (int j = 0; j < 9; j++) { w0[j] = wsm[j]; w1[j] = wsm[9 + j]; }
    const float b0 = wsm[18], b1v = wsm[19];
    float m0 = -1e30f, m1 = -1e30f;
    for (int dy = 0; dy < 4; dy++) {
      for (int dx = 0; dx < 4; dx++) {
        const float* ip = &img[(py * 4 + dy) * 68 + px * 4 + dx];
        float s0 = b0, s1 = b1v;
#pragma unroll
        for (int ky = 0; ky < 3; ky++) {
#pragma unroll
          for (int kx = 0; kx < 3; kx++) {
            float v = ip[ky * 68 + kx];
            s0 = fmaf(v, w0[ky * 3 + kx], s0);
            s1 = fmaf(v, w1[ky * 3 + kx], s1);
          }
        }
        m0 = fmaxf(m0, s0); m1 = fmaxf(m1, s1);
      }
    }
    p1[py * 16 + px] = fmaxf(m0, 0.f);
    p1[240 + py * 16 + px] = fmaxf(m1, 0.f);
  }
  __syncthreads();

  if (tid < 36) {
    int ch = tid / 9, rem = tid - ch * 9;
    int py = rem / 3, px = rem - py * 3;
    float m = -1e30f;
    for (int dy = 0; dy < 4; dy++) {
      for (int dx = 0; dx < 4; dx++) {
        int y = py * 4 + dy, xx = px * 4 + dx;
        float s = wsm[92 + ch];
#pragma unroll
        for (int ic = 0; ic < 2; ic++)
#pragma unroll
          for (int ky = 0; ky < 3; ky++)
#pragma unroll
            for (int kx = 0; kx < 3; kx++)
              s = fmaf(p1[ic * 240 + (y + ky) * 16 + xx + kx],
                       wsm[20 + ((ch * 2 + ic) * 3 + ky) * 3 + kx], s);
        m = fmaxf(m, s);
      }
    }
    p2[tid] = fmaxf(m, 0.f);
  }
  __syncthreads();

  unsigned short* fr = feat16 + ((long)t * B_ + b) * 16;
  if (tid < 8) {
    float s = fcb[tid];
#pragma unroll
    for (int j = 0; j < 36; j++) s = fmaf(p2[j], fcw[tid * 36 + j], s);
    fr[8 + tid] = f2bf(s);
  } else if (tid < 16) {
    fr[tid - 8] = f2bf(src[tid - 8]);
  }
}

// ---------------------------------------------------------------------------
// Kernel 1b: pack weight fragments bf16 (r8 layout verbatim).
// fragid = ((half*4+w)*8 + u)*9 + s; addr = fragid*512 + lane*8 shorts.
// s0..3 = OWN-half K (kf=4*half+s); s4..7 = PEER (kf=4*(1-half)+s-4); s8 = w_ih.
// ---------------------------------------------------------------------------
__global__ __launch_bounds__(256) void pack_kernel(
    const float* __restrict__ whh, const float* __restrict__ wih,
    unsigned short* __restrict__ spack)
{
  const int idx = blockIdx.x * 256 + threadIdx.x;   // 0..36863
  if (idx >= 8 * 8 * 9 * 64) return;
  const int lane = idx & 63;
  const int fragid = idx >> 6;          // 0..575
  const int s = fragid % 9;
  const int uw = fragid / 9;            // 0..63
  const int u = uw & 7;
  const int hw_ = uw >> 3;              // half*4 + w
  const int half = hw_ >> 2, w = hw_ & 3;
  const int col15 = lane & 15, ko8 = (lane >> 4) * 8;
  const int col = (u >> 1) * 256 + half * 128 + w * 32 + (u & 1) * 16 + col15;
  short8v v = {0, 0, 0, 0, 0, 0, 0, 0};
  if (s < 8) {
    const int kf = (s < 4) ? (4 * half + s) : (4 * (1 - half) + (s - 4));
    v = pack8(whh + col * 256 + kf * 32 + ko8);
  } else if (ko8 < 16) {
    v = pack8(wih + col * 16 + ko8);
  }
  *(short8v*)(spack + (size_t)idx * 8) = v;
}

// ---------------------------------------------------------------------------
// Kernel 2: LSTM, TWO-CHAIN interleaved pair exchange.
// 8 blocks = 4 batch-quads x 2 hidden halves; block (q,half) runs TWO
// independent 16-row chains (groups 2q, 2q+1) over its 128 dims, sharing ONE
// weight register file (weights are batch-independent — the key trick).
// r8 measured 4.8us/step with CU ~75% idle on the agent-scope exchange chain
// (VGPR 208, clean). Chain B's compute fills chain A's fabric latency.
// Registers: bfO+bfP -> AGPR (256 exactly); bfF arch-pinned (32);
// accA+accB arch (64); peak loads-in-flight 32 -> arch ~210.
// pqB issued AFTER the mid-barrier (barriers drain vmcnt — §5 lesson).
// ---------------------------------------------------------------------------
__global__ __launch_bounds__(256, 1) void lstm_kernel(
    const unsigned short* __restrict__ feat16,
    const float* __restrict__ bih, const float* __restrict__ bhh,
    const float* __restrict__ h0, const float* __restrict__ c0,
    const float* __restrict__ hw, const float* __restrict__ hdb,
    const unsigned short* __restrict__ spack,
    unsigned short* hb16, float* hpg, unsigned* flags,
    float* __restrict__ out)
{
  __shared__ __attribute__((aligned(16))) unsigned short hlsA[16 * 136];
  __shared__ __attribute__((aligned(16))) unsigned short hlsB[16 * 136];
  __shared__ float headpA[64], headpB[64];

  const int tid = threadIdx.x;
  const int w = tid >> 6, lane = tid & 63;
  const int q = blockIdx.x & 3, half = blockIdx.x >> 2;
  const int gidA = 4 * q + half,     pgidA = 4 * q + (1 - half);
  const int gidB = 4 * q + 2 + half, pgidB = 4 * q + 2 + (1 - half);
  const int R0A = q * 32, R0B = q * 32 + 16;
  const int D0 = half * 128, Dl = w * 32;
  const int col15 = lane & 15, ko8 = (lane >> 4) * 8, rb = (lane >> 4) * 4;
  const int ar = col15;
  const int pblk = blockIdx.x ^ 4;

  unsigned short* hbB2[2] = { hb16, hb16 + 32768 };

  const unsigned short* sbase =
      spack + (size_t)((half * 4 + w) * 8) * 9 * 512 + (size_t)lane * 8;
#define SFRAG(u, s) (*(const short8v*)(sbase + ((u) * 9 + (s)) * 512))
  short8v bfO[4][8], bfP[4][8], bfF[8];
#pragma unroll
  for (int u = 0; u < 8; u++) {
#pragma unroll
    for (int s = 0; s < 4; s++) bfO[s][u] = pinned_a(SFRAG(u, s));
#pragma unroll
    for (int s = 0; s < 4; s++) bfP[s][u] = pinned_a(SFRAG(u, 4 + s));
    bfF[u] = pinned(SFRAG(u, 8));
  }

  float bsr[8];
#pragma unroll
  for (int u = 0; u < 8; u++) {
    const int col = (u >> 1) * 256 + D0 + Dl + (u & 1) * 16 + col15;
    bsr[u] = bih[col] + bhh[col];
  }
  float hwr[2] = { hw[D0 + Dl + col15], hw[D0 + Dl + 16 + col15] };
  const float hdb0 = hdb[0];

  // ---- c-state for both chains; h0 -> LDS + publish both halves (buf 0)
  float csA[2][4], csB[2][4];
#pragma unroll
  for (int q2 = 0; q2 < 2; q2++)
#pragma unroll
    for (int rr = 0; rr < 4; rr++) {
      const int row = rb + rr, dloc = Dl + q2 * 16 + col15;
      csA[q2][rr] = c0[(R0A + row) * H_ + D0 + dloc];
      csB[q2][rr] = c0[(R0B + row) * H_ + D0 + dloc];
      unsigned short hvA = f2bf(h0[(R0A + row) * H_ + D0 + dloc]);
      unsigned short hvB = f2bf(h0[(R0B + row) * H_ + D0 + dloc]);
      hlsA[row * 136 + dloc] = hvA;
      hlsB[row * 136 + dloc] = hvB;
      __hip_atomic_store(hbB2[0] + (gidA * 16 + row) * 128 + dloc, hvA,
                         __ATOMIC_RELAXED, __HIP_MEMORY_SCOPE_AGENT);
      __hip_atomic_store(hbB2[0] + (gidB * 16 + row) * 128 + dloc, hvB,
                         __ATOMIC_RELAXED, __HIP_MEMORY_SCOPE_AGENT);
    }
  __syncthreads();   // drains vmcnt: h0 publishes acked before flag
  if (tid == 0)
    __hip_atomic_store(flags + blockIdx.x * 16, 1u,
                       __ATOMIC_RELEASE, __HIP_MEMORY_SCOPE_AGENT);

  const unsigned* pflag = flags + pblk * 16;

  for (int t = 0; t < T_; t++) {
    // ---- 1. poll peer (both chains covered by its one flag)
    {
      const unsigned need = (unsigned)(t + 1);
      unsigned v; long guard = 0;
      do {
        v = __hip_atomic_load(pflag, __ATOMIC_RELAXED, __HIP_MEMORY_SCOPE_AGENT);
      } while (v < need && ++guard < (1L << 22));
      __builtin_amdgcn_fence(__ATOMIC_ACQUIRE, "agent");
    }

    // ---- 2. issue chain-A peer loads + both feat frags + peer head partials
    const unsigned long long* hbr = (const unsigned long long*)hbB2[t & 1];
    unsigned long long pqA[8];
#pragma unroll
    for (int s = 0; s < 4; s++) {
      const unsigned long long* pr =
          hbr + (size_t)(pgidA * 16 + ar) * 32 + s * 8 + (ko8 >> 2);
      pqA[2 * s]     = __hip_atomic_load(pr,     __ATOMIC_RELAXED, __HIP_MEMORY_SCOPE_AGENT);
      pqA[2 * s + 1] = __hip_atomic_load(pr + 1, __ATOMIC_RELAXED, __HIP_MEMORY_SCOPE_AGENT);
    }
    short8v afA = (short8v){0, 0, 0, 0, 0, 0, 0, 0};
    short8v afB = (short8v){0, 0, 0, 0, 0, 0, 0, 0};
    if (ko8 < 16) {
      afA = *(const short8v*)(feat16 + ((size_t)t * B_ + R0A + ar) * 16 + ko8);
      afB = *(const short8v*)(feat16 + ((size_t)t * B_ + R0B + ar) * 16 + ko8);
    }
    float hp0 = 0.f, hp1 = 0.f, hp2 = 0.f, hp3 = 0.f;
    if (half == 0 && t > 0) {
      const float* pp = nullptr;
      if (tid < 16)                 pp = hpg + (t & 1) * 1024 + pgidA * 64 + tid * 4;
      else if (tid >= 64 && tid < 80) pp = hpg + (t & 1) * 1024 + pgidB * 64 + (tid - 64) * 4;
      if (pp) {
        hp0 = __hip_atomic_load(pp + 0, __ATOMIC_RELAXED, __HIP_MEMORY_SCOPE_AGENT);
        hp1 = __hip_atomic_load(pp + 1, __ATOMIC_RELAXED, __HIP_MEMORY_SCOPE_AGENT);
        hp2 = __hip_atomic_load(pp + 2, __ATOMIC_RELAXED, __HIP_MEMORY_SCOPE_AGENT);
        hp3 = __hip_atomic_load(pp + 3, __ATOMIC_RELAXED, __HIP_MEMORY_SCOPE_AGENT);
      }
    }

    // ---- 3./4. own-half + feat MFMAs for both chains (hides pqA RTT)
    f32x4 accA[8], accB[8];
#pragma unroll
    for (int u = 0; u < 8; u++) accA[u] = (f32x4){0.f, 0.f, 0.f, 0.f};
#pragma unroll
    for (int u = 0; u < 8; u++) accB[u] = (f32x4){0.f, 0.f, 0.f, 0.f};
#pragma unroll
    for (int s = 0; s < 4; s++) {
      short8v a = *(const short8v*)&hlsA[ar * 136 + s * 32 + ko8];
#pragma unroll
      for (int u = 0; u < 8; u++) accA[u] = MFMA(a, bfO[s][u], accA[u]);
    }
#pragma unroll
    for (int u = 0; u < 8; u++) accA[u] = MFMA(afA, bfF[u], accA[u]);
#pragma unroll
    for (int s = 0; s < 4; s++) {
      short8v a = *(const short8v*)&hlsB[ar * 136 + s * 32 + ko8];
#pragma unroll
      for (int u = 0; u < 8; u++) accB[u] = MFMA(a, bfO[s][u], accB[u]);
    }
#pragma unroll
    for (int u = 0; u < 8; u++) accB[u] = MFMA(afB, bfF[u], accB[u]);

    // ---- 4.5 read own head partials (t-1) into regs before mid-barrier
    float hsum = 0.f;
    if (half == 0 && t > 0) {
      if (tid < 16)
        hsum = headpA[tid] + headpA[16 + tid] + headpA[32 + tid] + headpA[48 + tid];
      else if (tid >= 64 && tid < 80) {
        int r = tid - 64;
        hsum = headpB[r] + headpB[16 + r] + headpB[32 + r] + headpB[48 + r];
      }
    }

    __syncthreads();   // mid: all hls/headp reads done; pqA/feat/hpg drained

    // ---- 6. out[t-1] (half-0 block; wave0 = chain A rows, wave1 = chain B)
    if (half == 0 && t > 0) {
      if (tid < 16)
        out[(long)(R0A + tid) * T_ + (t - 1)] = hdb0 + hsum + hp0 + hp1 + hp2 + hp3;
      else if (tid >= 64 && tid < 80)
        out[(long)(R0B + (tid - 64)) * T_ + (t - 1)] = hdb0 + hsum + hp0 + hp1 + hp2 + hp3;
    }

    // ---- 7. issue chain-B peer loads (AFTER barrier: no drain stall)
    unsigned long long pqB[8];
#pragma unroll
    for (int s = 0; s < 4; s++) {
      const unsigned long long* pr =
          hbr + (size_t)(pgidB * 16 + ar) * 32 + s * 8 + (ko8 >> 2);
      pqB[2 * s]     = __hip_atomic_load(pr,     __ATOMIC_RELAXED, __HIP_MEMORY_SCOPE_AGENT);
      pqB[2 * s + 1] = __hip_atomic_load(pr + 1, __ATOMIC_RELAXED, __HIP_MEMORY_SCOPE_AGENT);
    }

    // ---- 8. chain-A peer MFMAs
#pragma unroll
    for (int s = 0; s < 4; s++) {
      union { unsigned long long qv[2]; short8v v; } u_;
      u_.qv[0] = pqA[2 * s]; u_.qv[1] = pqA[2 * s + 1];
#pragma unroll
      for (int u = 0; u < 8; u++) accA[u] = MFMA(u_.v, bfP[s][u], accA[u]);
    }

    unsigned short* hbw = hbB2[(t + 1) & 1];

    // ---- 9. chain-A elementwise + publish (hides pqB RTT)
    {
      float ps[4] = {0.f, 0.f, 0.f, 0.f};
#pragma unroll
      for (int q2 = 0; q2 < 2; q2++)
#pragma unroll
        for (int rr = 0; rr < 4; rr++) {
          float i_ = accA[0 + q2][rr] + bsr[0 + q2];
          float f_ = accA[2 + q2][rr] + bsr[2 + q2];
          float g_ = accA[4 + q2][rr] + bsr[4 + q2];
          float o_ = accA[6 + q2][rr] + bsr[6 + q2];
          float cn = sigm(f_) * csA[q2][rr] + sigm(i_) * tanh_f(g_);
          csA[q2][rr] = cn;
          float hn = sigm(o_) * tanh_f(cn);
          const int row = rb + rr, dloc = Dl + q2 * 16 + col15;
          unsigned short hv = f2bf(hn);
          hlsA[row * 136 + dloc] = hv;
          __hip_atomic_store(hbw + (gidA * 16 + row) * 128 + dloc, hv,
                             __ATOMIC_RELAXED, __HIP_MEMORY_SCOPE_AGENT);
          ps[rr] += hn * hwr[q2];
        }
#pragma unroll
      for (int off = 1; off <= 8; off <<= 1)
#pragma unroll
        for (int rr = 0; rr < 4; rr++) ps[rr] += __shfl_xor(ps[rr], off);
      if (col15 == 0)
#pragma unroll
        for (int rr = 0; rr < 4; rr++) {
          headpA[w * 16 + rb + rr] = ps[rr];
          __hip_atomic_store(hpg + ((t + 1) & 1) * 1024 + gidA * 64 + (rb + rr) * 4 + w,
                             ps[rr], __ATOMIC_RELAXED, __HIP_MEMORY_SCOPE_AGENT);
        }
    }

    // ---- 10. chain-B peer MFMAs
#pragma unroll
    for (int s = 0; s < 4; s++) {
      union { unsigned long long qv[2]; short8v v; } u_;
      u_.qv[0] = pqB[2 * s]; u_.qv[1] = pqB[2 * s + 1];
#pragma unroll
      for (int u = 0; u < 8; u++) accB[u] = MFMA(u_.v, bfP[s][u], accB[u]);
    }

    // ---- 11. chain-B elementwise + publish
    {
      float ps[4] = {0.f, 0.f, 0.f, 0.f};
#pragma unroll
      for (int q2 = 0; q2 < 2; q2++)
#pragma unroll
        for (int rr = 0; rr < 4; rr++) {
          float i_ = accB[0 + q2][rr] + bsr[0 + q2];
          float f_ = accB[2 + q2][rr] + bsr[2 + q2];
          float g_ = accB[4 + q2][rr] + bsr[4 + q2];
          float o_ = accB[6 + q2][rr] + bsr[6 + q2];
          float cn = sigm(f_) * csB[q2][rr] + sigm(i_) * tanh_f(g_);
          csB[q2][rr] = cn;
          float hn = sigm(o_) * tanh_f(cn);
          const int row = rb + rr, dloc = Dl + q2 * 16 + col15;
          unsigned short hv = f2bf(hn);
          hlsB[row * 136 + dloc] = hv;
          __hip_atomic_store(hbw + (gidB * 16 + row) * 128 + dloc, hv,
                             __ATOMIC_RELAXED, __HIP_MEMORY_SCOPE_AGENT);
          ps[rr] += hn * hwr[q2];
        }
#pragma unroll
      for (int off = 1; off <= 8; off <<= 1)
#pragma unroll
        for (int rr = 0; rr < 4; rr++) ps[rr] += __shfl_xor(ps[rr], off);
      if (col15 == 0)
#pragma unroll
        for (int rr = 0; rr < 4; rr++) {
          headpB[w * 16 + rb + rr] = ps[rr];
          __hip_atomic_store(hpg + ((t + 1) & 1) * 1024 + gidB * 64 + (rb + rr) * 4 + w,
                             ps[rr], __ATOMIC_RELAXED, __HIP_MEMORY_SCOPE_AGENT);
        }
    }

    __syncthreads();   // end: all publishes/out/hp stores drained (vmcnt 0)
    if (tid == 0)
      __hip_atomic_store(flags + blockIdx.x * 16, (unsigned)(t + 2),
                         __ATOMIC_RELEASE, __HIP_MEMORY_SCOPE_AGENT);
  }

  // ---- final out column (t = T-1)
  if (half == 0) {
    {
      const unsigned need = (unsigned)(T_ + 1);
      unsigned v; long guard = 0;
      do {
        v = __hip_atomic_load(pflag, __ATOMIC_RELAXED, __HIP_MEMORY_SCOPE_AGENT);
      } while (v < need && ++guard < (1L << 22));
      __builtin_amdgcn_fence(__ATOMIC_ACQUIRE, "agent");
    }
    if (tid < 16) {
      float s = hdb0 + headpA[tid] + headpA[16 + tid] + headpA[32 + tid] + headpA[48 + tid];
      const float* pp = hpg + (T_ & 1) * 1024 + pgidA * 64 + tid * 4;
#pragma unroll
      for (int i = 0; i < 4; i++)
        s += __hip_atomic_load(pp + i, __ATOMIC_RELAXED, __HIP_MEMORY_SCOPE_AGENT);
      out[(long)(R0A + tid) * T_ + (T_ - 1)] = s;
    } else if (tid >= 64 && tid < 80) {
      int r = tid - 64;
      float s = hdb0 + headpB[r] + headpB[16 + r] + headpB[32 + r] + headpB[48 + r];
      const float* pp = hpg + (T_ & 1) * 1024 + pgidB * 64 + r * 4;
#pragma unroll
      for (int i = 0; i < 4; i++)
        s += __hip_atomic_load(pp + i, __ATOMIC_RELAXED, __HIP_MEMORY_SCOPE_AGENT);
      out[(long)(R0B + r) * T_ + (T_ - 1)] = s;
    }
  }
}

// ---------------------------------------------------------------------------
extern "C" void kernel_launch(void* const* d_in, const int* in_sizes, int n_in,
                              void* d_out, int out_size, void* d_ws, size_t ws_size,
                              hipStream_t stream) {
  const float* x   = (const float*)d_in[0];
  const float* c1w = (const float*)d_in[1];
  const float* c1b = (const float*)d_in[2];
  const float* c2w = (const float*)d_in[3];
  const float* c2b = (const float*)d_in[4];
  const float* fcw = (const float*)d_in[5];
  const float* fcb = (const float*)d_in[6];
  const float* wih = (const float*)d_in[7];
  const float* whh = (const float*)d_in[8];
  const float* bih = (const float*)d_in[9];
  const float* bhh = (const float*)d_in[10];
  const float* hw  = (const float*)d_in[11];
  const float* hdb = (const float*)d_in[12];
  const float* h0  = (const float*)d_in[13];
  const float* c0  = (const float*)d_in[14];
  float* out = (float*)d_out;

  if (ws_size < WS_NEED) return;
  char* ws = (char*)d_ws;
  unsigned short* feat16 = (unsigned short*)ws;
  unsigned short* spack  = (unsigned short*)(ws + FEAT16_B);
  unsigned short* hb16   = (unsigned short*)(ws + FEAT16_B + SPACK_B);
  float* hpg             = (float*)(ws + FEAT16_B + SPACK_B + HB_B);
  unsigned* flags        = (unsigned*)(ws + FEAT16_B + SPACK_B + HB_B + HP_B);

  cnn_kernel<<<dim3(B_ * T_), dim3(256), 0, stream>>>(
      x, c1w, c1b, c2w, c2b, fcw, fcb, feat16, flags);
  pack_kernel<<<dim3(144), dim3(256), 0, stream>>>(whh, wih, spack);
  lstm_kernel<<<dim3(8), dim3(256), 0, stream>>>(
      feat16, bih, bhh, h0, c0, hw, hdb, spack, hb16, hpg, flags, out);
}